// Round 5
// baseline (761.719 us; speedup 1.0000x reference)
//
#include <hip/hip_runtime.h>

#define HID 128
#define NLAYERS 4
#define MAXBUCK 1600     // >= ceil(100000/64)=1563
#define CHUNK 2048

typedef __attribute__((ext_vector_type(8))) short bf16x8;
typedef __attribute__((ext_vector_type(8))) unsigned short u16x8;
typedef __attribute__((ext_vector_type(4))) float f32x4;

static __device__ __forceinline__ float bf2f(unsigned short u) {
    return __uint_as_float(((unsigned)u) << 16);
}
static __device__ __forceinline__ unsigned short f2bf(float f) {
    unsigned u = __float_as_uint(f);
    return (unsigned short)((u + 0x7FFF + ((u >> 16) & 1)) >> 16);   // RNE
}

// ---------------- preprocessing: deterministic two-level counting sort ----------------

// per-chunk LDS histogram over coarse buckets (64 dst nodes each); no global atomics
__global__ __launch_bounds__(256) void bin1(const int* __restrict__ dst,
                                            int* __restrict__ cnt2d, int E, int nbuck) {
    __shared__ int h[MAXBUCK];
    int tid = threadIdx.x;
    for (int i = tid; i < nbuck; i += 256) h[i] = 0;
    __syncthreads();
    int e0 = blockIdx.x * CHUNK;
    int e1 = min(e0 + CHUNK, E);
    for (int e = e0 + tid; e < e1; e += 256) atomicAdd(&h[dst[e] >> 6], 1);
    __syncthreads();
    for (int i = tid; i < nbuck; i += 256)
        cnt2d[(size_t)blockIdx.x * nbuck + i] = h[i];
}

// per-bucket exclusive prefix over chunks (in place); column sums out
__global__ void colscan(int* __restrict__ cnt2d, int* __restrict__ colsum,
                        int nchunks, int nbuck) {
    int b = blockIdx.x * blockDim.x + threadIdx.x;
    if (b >= nbuck) return;
    int run = 0;
    for (int c = 0; c < nchunks; ++c) {
        size_t idx = (size_t)c * nbuck + b;
        int v = cnt2d[idx];
        cnt2d[idx] = run;
        run += v;
    }
    colsum[b] = run;
}

// exclusive scan of colsum -> base[0..nbuck] (base[b+1] = incl prefix)
__global__ __launch_bounds__(256) void basescan(const int* __restrict__ colsum,
                                                int* __restrict__ base, int nbuck) {
    __shared__ int part[256];
    int tid = threadIdx.x;
    const int per = 7;   // 256*7=1792 >= MAXBUCK
    int loc[per];
    int run = 0;
    for (int i = 0; i < per; ++i) {
        int idx = tid * per + i;
        int v = (idx < nbuck) ? colsum[idx] : 0;
        run += v;
        loc[i] = run;
    }
    part[tid] = run;
    __syncthreads();
    for (int off = 1; off < 256; off <<= 1) {
        int t = (tid >= off) ? part[tid - off] : 0;
        __syncthreads();
        part[tid] += t;
        __syncthreads();
    }
    int prev = tid ? part[tid - 1] : 0;
    if (tid == 0) base[0] = 0;
    for (int i = 0; i < per; ++i) {
        int idx = tid * per + i;
        if (idx < nbuck) base[idx + 1] = prev + loc[i];
    }
}

// scatter edges into coarse-bucket regions, packed src | (dst&63)<<20
__global__ __launch_bounds__(256) void bin2(const int* __restrict__ src, const int* __restrict__ dst,
                                            const int* __restrict__ cnt2d, const int* __restrict__ base,
                                            unsigned* __restrict__ ecoarse, int E, int nbuck) {
    __shared__ int cur[MAXBUCK];
    int tid = threadIdx.x;
    for (int i = tid; i < nbuck; i += 256)
        cur[i] = base[i] + cnt2d[(size_t)blockIdx.x * nbuck + i];
    __syncthreads();
    int e0 = blockIdx.x * CHUNK;
    int e1 = min(e0 + CHUNK, E);
    for (int e = e0 + tid; e < e1; e += 256) {
        int d = dst[e];
        int b = d >> 6;
        int pos = atomicAdd(&cur[b], 1);
        ecoarse[pos] = (unsigned)src[e] | ((unsigned)(d & 63) << 20);
    }
}

// per-bucket LDS counting sort by dlocal -> src-only CSR + rowp + dis (deg from histogram)
__global__ __launch_bounds__(256) void finesort(const unsigned* __restrict__ ecoarse,
                                                const int* __restrict__ base,
                                                float* __restrict__ dis,
                                                unsigned* __restrict__ csr, int* __restrict__ rowp,
                                                int N, int E) {
    __shared__ int h[64], off[64];
    int b = blockIdx.x, tid = threadIdx.x;
    if (tid < 64) h[tid] = 0;
    __syncthreads();
    int s = base[b], e = base[b + 1];
    for (int i = s + tid; i < e; i += 256) atomicAdd(&h[ecoarse[i] >> 20], 1);
    __syncthreads();
    if (tid == 0) {
        int run = 0;
        for (int i = 0; i < 64; ++i) { off[i] = run; run += h[i]; }
    }
    __syncthreads();
    if (tid < 64) {
        int node = b * 64 + tid;
        if (node < N) {
            rowp[node] = s + off[tid];
            dis[node] = rsqrtf((float)h[tid] + 1.0f);   // in-degree + self-loop
        }
        h[tid] = off[tid];   // reuse as cursors
    }
    if (b == 0 && tid == 0) rowp[N] = E;
    __syncthreads();
    for (int i = s + tid; i < e; i += 256) {
        unsigned v = ecoarse[i];
        int dl = v >> 20;
        int pos = atomicAdd(&h[dl], 1);
        csr[s + pos] = v & 0xFFFFF;
    }
}

// ---------------- weight prep: transpose + convert to bf16 ----------------

__global__ void wprep(const float* __restrict__ W1, const float* __restrict__ convW,
                      const float* __restrict__ W2, unsigned short* __restrict__ W1t,
                      unsigned short* __restrict__ convWt, unsigned short* __restrict__ W2t) {
    int r = blockIdx.x;
    int k = threadIdx.x;
    const float* src;
    unsigned short* dst;
    int ncols, n;
    if (r < 128) { src = W1; dst = W1t; n = r; ncols = 128; }
    else if (r < 640) {
        int l = (r - 128) >> 7; n = (r - 128) & 127;
        src = convW + (size_t)l * 16384; dst = convWt + (size_t)l * 16384; ncols = 128;
    } else { src = W2; dst = W2t; n = r - 640; ncols = 64; }
    dst[(size_t)n * 128 + k] = f2bf(src[(size_t)k * ncols + n]);
}

__global__ void xcast(const float* __restrict__ x, unsigned short* __restrict__ xb, int n8) {
    int i = blockIdx.x * blockDim.x + threadIdx.x;
    if (i >= n8) return;
    float4 v0 = *(const float4*)&x[(size_t)i * 8];
    float4 v1 = *(const float4*)&x[(size_t)i * 8 + 4];
    u16x8 o;
    o[0] = f2bf(v0.x); o[1] = f2bf(v0.y); o[2] = f2bf(v0.z); o[3] = f2bf(v0.w);
    o[4] = f2bf(v1.x); o[5] = f2bf(v1.y); o[6] = f2bf(v1.z); o[7] = f2bf(v1.w);
    *(u16x8*)&xb[(size_t)i * 8] = o;
}

// ---------------- MFMA GEMM: C[n,128] = A[n,128] @ Wt^T (+bias), all bf16 ----------------

template <bool BIAS>
__global__ __launch_bounds__(256, 2) void gemm128_mfma(
    const unsigned short* __restrict__ A, const unsigned short* __restrict__ Bt,
    const float* __restrict__ bias, unsigned short* __restrict__ C, int nrows) {
    int wid = threadIdx.x >> 6, lane = threadIdx.x & 63;
    int l15 = lane & 15, l4 = lane >> 4;

    bf16x8 b[8][4];
#pragma unroll
    for (int nt = 0; nt < 8; ++nt)
#pragma unroll
        for (int ks = 0; ks < 4; ++ks)
            b[nt][ks] = *(const bf16x8*)&Bt[(size_t)(nt * 16 + l15) * 128 + ks * 32 + l4 * 8];
    float bb[8];
    if (BIAS) {
#pragma unroll
        for (int nt = 0; nt < 8; ++nt) bb[nt] = bias[nt * 16 + l15];
    }

    for (int s2 = 0; s2 < 2; ++s2) {
        int row0 = (blockIdx.x * 8 + wid * 2 + s2) * 16;
        if (row0 >= nrows) break;
        int ar = min(row0 + l15, nrows - 1);
        bf16x8 a[4];
#pragma unroll
        for (int ks = 0; ks < 4; ++ks)
            a[ks] = *(const bf16x8*)&A[(size_t)ar * 128 + ks * 32 + l4 * 8];
        f32x4 acc[8] = {};
#pragma unroll
        for (int ks = 0; ks < 4; ++ks)
#pragma unroll
            for (int nt = 0; nt < 8; ++nt)
                acc[nt] = __builtin_amdgcn_mfma_f32_16x16x32_bf16(a[ks], b[nt][ks], acc[nt], 0, 0, 0);
#pragma unroll
        for (int nt = 0; nt < 8; ++nt) {
            int col = nt * 16 + l15;
#pragma unroll
            for (int r = 0; r < 4; ++r) {
                int row = row0 + l4 * 4 + r;
                if (row < nrows) {
                    float v = acc[nt][r];
                    if (BIAS) v += bb[nt];
                    C[(size_t)row * 128 + col] = f2bf(v);
                }
            }
        }
    }
}

// ---------------- final GEMM: out = 0.6*Z1@W2 + 0.1*(Z2+Z3+Z4+Z5)@W2 + b2 ----------------

__global__ __launch_bounds__(256, 2) void gemm_final(
    const unsigned short* __restrict__ z0, const unsigned short* __restrict__ z1,
    const unsigned short* __restrict__ z2, const unsigned short* __restrict__ z3,
    const unsigned short* __restrict__ z4, const unsigned short* __restrict__ Bt,
    const float* __restrict__ bias, float* __restrict__ out, int nrows) {
    int wid = threadIdx.x >> 6, lane = threadIdx.x & 63;
    int l15 = lane & 15, l4 = lane >> 4;

    bf16x8 b[4][4];
#pragma unroll
    for (int nt = 0; nt < 4; ++nt)
#pragma unroll
        for (int ks = 0; ks < 4; ++ks)
            b[nt][ks] = *(const bf16x8*)&Bt[(size_t)(nt * 16 + l15) * 128 + ks * 32 + l4 * 8];
    float bb[4];
#pragma unroll
    for (int nt = 0; nt < 4; ++nt) bb[nt] = bias[nt * 16 + l15];

    const unsigned short* zs[5] = { z0, z1, z2, z3, z4 };

    for (int s2 = 0; s2 < 2; ++s2) {
        int row0 = (blockIdx.x * 8 + wid * 2 + s2) * 16;
        if (row0 >= nrows) break;
        int ar = min(row0 + l15, nrows - 1);
        bf16x8 a[5][4];
#pragma unroll
        for (int st = 0; st < 5; ++st)
#pragma unroll
            for (int ks = 0; ks < 4; ++ks)
                a[st][ks] = *(const bf16x8*)&zs[st][(size_t)ar * 128 + ks * 32 + l4 * 8];
        f32x4 acc0[4] = {};
        f32x4 acc1[4] = {};
#pragma unroll
        for (int st = 0; st < 5; ++st)
#pragma unroll
            for (int ks = 0; ks < 4; ++ks)
#pragma unroll
                for (int nt = 0; nt < 4; ++nt) {
                    if (st == 0)
                        acc0[nt] = __builtin_amdgcn_mfma_f32_16x16x32_bf16(a[0][ks], b[nt][ks], acc0[nt], 0, 0, 0);
                    else
                        acc1[nt] = __builtin_amdgcn_mfma_f32_16x16x32_bf16(a[st][ks], b[nt][ks], acc1[nt], 0, 0, 0);
                }
#pragma unroll
        for (int nt = 0; nt < 4; ++nt) {
            int col = nt * 16 + l15;
#pragma unroll
            for (int r = 0; r < 4; ++r) {
                int row = row0 + l4 * 4 + r;
                if (row < nrows)
                    out[(size_t)row * 64 + col] = 0.6f * acc0[nt][r] + 0.1f * acc1[nt][r] + bb[nt];
            }
        }
    }
}

// ---------------- fused SpMM(bf16 gather) + self-loop + bias + ReLU, bf16 out ----------------
// 16 lanes/node; src-only CSR; w = dis[src], dis[dst] factored out of the sum.

__global__ __launch_bounds__(256) void spmm_kernel(
    const unsigned short* __restrict__ xwb, const int* __restrict__ rowp,
    const unsigned* __restrict__ csr, const float* __restrict__ dis,
    const float* __restrict__ bias, unsigned short* __restrict__ Z, int n) {
    int l = threadIdx.x & 15;
    int node = blockIdx.x * 16 + (threadIdx.x >> 4);
    if (node >= n) return;
    const u16x8* xw8 = (const u16x8*)xwb;

    float acc[8] = {};
    int beg = rowp[node], end = rowp[node + 1];
    int e = beg;
    for (; e + 4 <= end; e += 4) {
        unsigned s0 = csr[e];
        unsigned s1 = csr[e + 1];
        unsigned s2 = csr[e + 2];
        unsigned s3 = csr[e + 3];
        float w0 = dis[s0];
        float w1 = dis[s1];
        float w2 = dis[s2];
        float w3 = dis[s3];
        u16x8 x0 = xw8[(size_t)s0 * 16 + l];
        u16x8 x1 = xw8[(size_t)s1 * 16 + l];
        u16x8 x2 = xw8[(size_t)s2 * 16 + l];
        u16x8 x3 = xw8[(size_t)s3 * 16 + l];
#pragma unroll
        for (int j = 0; j < 8; ++j) {
            acc[j] = fmaf(w0, bf2f(x0[j]), acc[j]);
            acc[j] = fmaf(w1, bf2f(x1[j]), acc[j]);
            acc[j] = fmaf(w2, bf2f(x2[j]), acc[j]);
            acc[j] = fmaf(w3, bf2f(x3[j]), acc[j]);
        }
    }
    for (; e < end; ++e) {
        unsigned s0 = csr[e];
        float w0 = dis[s0];
        u16x8 x0 = xw8[(size_t)s0 * 16 + l];
#pragma unroll
        for (int j = 0; j < 8; ++j) acc[j] = fmaf(w0, bf2f(x0[j]), acc[j]);
    }

    float d = dis[node];
    float d2 = d * d;
    u16x8 xs = xw8[(size_t)node * 16 + l];
    float4 b0 = *(const float4*)&bias[l * 8];
    float4 b1 = *(const float4*)&bias[l * 8 + 4];
    float bbv[8] = { b0.x, b0.y, b0.z, b0.w, b1.x, b1.y, b1.z, b1.w };
    u16x8 ov;
#pragma unroll
    for (int j = 0; j < 8; ++j)
        ov[j] = f2bf(fmaxf(fmaf(d, acc[j], fmaf(d2, bf2f(xs[j]), bbv[j])), 0.f));
    *(u16x8*)&Z[(size_t)node * HID + l * 8] = ov;
}

// ---------------- launcher ----------------

extern "C" void kernel_launch(void* const* d_in, const int* in_sizes, int n_in,
                              void* d_out, int out_size, void* d_ws, size_t ws_size,
                              hipStream_t stream) {
    const float* x     = (const float*)d_in[0];
    const int*   ei    = (const int*)d_in[1];
    const float* W1    = (const float*)d_in[2];
    const float* b1    = (const float*)d_in[3];
    const float* convW = (const float*)d_in[4];
    const float* convB = (const float*)d_in[5];
    const float* W2    = (const float*)d_in[6];
    const float* b2    = (const float*)d_in[7];

    const int N = in_sizes[0] / HID;
    const int E = in_sizes[1] / 2;
    const int* src = ei;
    const int* dst = ei + E;
    const int nbuck = (N + 63) / 64;
    const int nchunks = (E + CHUNK - 1) / CHUNK;

    char* p = (char*)d_ws;
    auto alloc = [&](size_t bytes) {
        void* q = (void*)p;
        p += (bytes + 255) & ~(size_t)255;
        return q;
    };
    float* dis      = (float*)alloc((size_t)N * 4);
    int*   rowp     = (int*)alloc((size_t)(N + 1) * 4);
    int*   base     = (int*)alloc((size_t)(nbuck + 1) * 4);
    int*   colsum   = (int*)alloc((size_t)nbuck * 4);
    int*   cnt2d    = (int*)alloc((size_t)nchunks * nbuck * 4);
    unsigned* ecoarse = (unsigned*)alloc((size_t)E * 4);
    unsigned* csr   = (unsigned*)alloc((size_t)E * 4);
    unsigned short* xb = (unsigned short*)alloc((size_t)N * HID * 2);
    unsigned short* xw = (unsigned short*)alloc((size_t)N * HID * 2);
    unsigned short* Zs[5];
    for (int i = 0; i < 4; ++i) Zs[i] = (unsigned short*)alloc((size_t)N * HID * 2);
    Zs[4] = xb;   // alias: xb dead after gemm1
    unsigned short* W1t    = (unsigned short*)alloc(128 * 128 * 2);
    unsigned short* convWt = (unsigned short*)alloc((size_t)NLAYERS * 128 * 128 * 2);
    unsigned short* W2t    = (unsigned short*)alloc(64 * 128 * 2);

    const int gemmBlocks = (N + 127) / 128;

    // --- weight prep + x cast ---
    wprep<<<704, 128, 0, stream>>>(W1, convW, W2, W1t, convWt, W2t);
    xcast<<<(N * 16 + 255) / 256, 256, 0, stream>>>(x, xb, N * 16);

    // --- graph preprocessing: two-level deterministic counting sort ---
    bin1<<<nchunks, 256, 0, stream>>>(dst, cnt2d, E, nbuck);
    colscan<<<(nbuck + 255) / 256, 256, 0, stream>>>(cnt2d, colsum, nchunks, nbuck);
    basescan<<<1, 256, 0, stream>>>(colsum, base, nbuck);
    bin2<<<nchunks, 256, 0, stream>>>(src, dst, cnt2d, base, ecoarse, E, nbuck);
    finesort<<<nbuck, 256, 0, stream>>>(ecoarse, base, dis, csr, rowp, N, E);

    // --- Z1 = bf16(x @ W1 + b1) ---
    gemm128_mfma<true><<<gemmBlocks, 256, 0, stream>>>(xb, W1t, b1, Zs[0], N);

    // --- 4 GCN layers ---
    for (int l = 0; l < NLAYERS; ++l) {
        gemm128_mfma<false><<<gemmBlocks, 256, 0, stream>>>(
            Zs[l], convWt + (size_t)l * 16384, nullptr, xw, N);
        spmm_kernel<<<(N + 15) / 16, 256, 0, stream>>>(
            xw, rowp, csr, dis, convB + (size_t)l * HID, Zs[l + 1], N);
    }

    // --- out = 0.6*Z1@W2 + 0.1*(Z2+..+Z5)@W2 + b2 ---
    gemm_final<<<gemmBlocks, 256, 0, stream>>>(
        Zs[0], Zs[1], Zs[2], Zs[3], Zs[4], W2t, b2, (float*)d_out, N);
}

// Round 8
// 631.078 us; speedup vs baseline: 1.2070x; 1.2070x over previous
//
#include <hip/hip_runtime.h>

#define HID 128
#define NLAYERS 4
#define MAXBUCK 1600     // >= ceil(100000/64)=1563
#define CHUNK 2048

typedef __attribute__((ext_vector_type(8))) short bf16x8;
typedef __attribute__((ext_vector_type(8))) unsigned short u16x8;
typedef __attribute__((ext_vector_type(4))) float f32x4;

static __device__ __forceinline__ float bf2f(unsigned short u) {
    return __uint_as_float(((unsigned)u) << 16);
}
static __device__ __forceinline__ unsigned short f2bf(float f) {
    unsigned u = __float_as_uint(f);
    return (unsigned short)((u + 0x7FFF + ((u >> 16) & 1)) >> 16);   // RNE
}

// ---------------- preprocessing: deterministic two-level counting sort ----------------

// per-chunk LDS histogram over coarse buckets (64 dst nodes each); no global atomics
__global__ __launch_bounds__(256) void bin1(const int* __restrict__ dst,
                                            int* __restrict__ cnt2d, int E, int nbuck) {
    __shared__ int h[MAXBUCK];
    int tid = threadIdx.x;
    for (int i = tid; i < nbuck; i += 256) h[i] = 0;
    __syncthreads();
    int e0 = blockIdx.x * CHUNK;
    int e1 = min(e0 + CHUNK, E);
    for (int e = e0 + tid; e < e1; e += 256) atomicAdd(&h[dst[e] >> 6], 1);
    __syncthreads();
    for (int i = tid; i < nbuck; i += 256)
        cnt2d[(size_t)blockIdx.x * nbuck + i] = h[i];
}

// wave-parallel per-bucket exclusive prefix over chunks (in place); column sums out.
// one 64-lane wave per bucket; shuffle-scan 64 chunks per step.
__global__ __launch_bounds__(256) void colscan(int* __restrict__ cnt2d, int* __restrict__ colsum,
                                               int nchunks, int nbuck) {
    int b = blockIdx.x * 4 + (threadIdx.x >> 6);
    int lane = threadIdx.x & 63;
    if (b >= nbuck) return;
    int run = 0;
    for (int c0 = 0; c0 < nchunks; c0 += 64) {
        int c = c0 + lane;
        int v = (c < nchunks) ? cnt2d[(size_t)c * nbuck + b] : 0;
        int incl = v;
#pragma unroll
        for (int off = 1; off < 64; off <<= 1) {
            int t = __shfl_up(incl, off, 64);
            if (lane >= off) incl += t;
        }
        if (c < nchunks) cnt2d[(size_t)c * nbuck + b] = run + incl - v;
        run += __shfl(incl, 63, 64);
    }
    if (lane == 0) colsum[b] = run;
}

// exclusive scan of colsum -> base[0..nbuck] (base[b+1] = incl prefix)
__global__ __launch_bounds__(256) void basescan(const int* __restrict__ colsum,
                                                int* __restrict__ base, int nbuck) {
    __shared__ int part[256];
    int tid = threadIdx.x;
    const int per = 7;   // 256*7=1792 >= MAXBUCK
    int loc[per];
    int run = 0;
    for (int i = 0; i < per; ++i) {
        int idx = tid * per + i;
        int v = (idx < nbuck) ? colsum[idx] : 0;
        run += v;
        loc[i] = run;
    }
    part[tid] = run;
    __syncthreads();
    for (int off = 1; off < 256; off <<= 1) {
        int t = (tid >= off) ? part[tid - off] : 0;
        __syncthreads();
        part[tid] += t;
        __syncthreads();
    }
    int prev = tid ? part[tid - 1] : 0;
    if (tid == 0) base[0] = 0;
    for (int i = 0; i < per; ++i) {
        int idx = tid * per + i;
        if (idx < nbuck) base[idx + 1] = prev + loc[i];
    }
}

// scatter edges into coarse-bucket regions, packed src | (dst&63)<<20
__global__ __launch_bounds__(256) void bin2(const int* __restrict__ src, const int* __restrict__ dst,
                                            const int* __restrict__ cnt2d, const int* __restrict__ base,
                                            unsigned* __restrict__ ecoarse, int E, int nbuck) {
    __shared__ int cur[MAXBUCK];
    int tid = threadIdx.x;
    for (int i = tid; i < nbuck; i += 256)
        cur[i] = base[i] + cnt2d[(size_t)blockIdx.x * nbuck + i];
    __syncthreads();
    int e0 = blockIdx.x * CHUNK;
    int e1 = min(e0 + CHUNK, E);
    for (int e = e0 + tid; e < e1; e += 256) {
        int d = dst[e];
        int b = d >> 6;
        int pos = atomicAdd(&cur[b], 1);
        ecoarse[pos] = (unsigned)src[e] | ((unsigned)(d & 63) << 20);
    }
}

// per-bucket LDS counting sort by dlocal -> src-only CSR + rowp + dis (deg from histogram)
__global__ __launch_bounds__(256) void finesort(const unsigned* __restrict__ ecoarse,
                                                const int* __restrict__ base,
                                                float* __restrict__ dis,
                                                unsigned* __restrict__ csr, int* __restrict__ rowp,
                                                int N, int E) {
    __shared__ int h[64], off[64];
    int b = blockIdx.x, tid = threadIdx.x;
    if (tid < 64) h[tid] = 0;
    __syncthreads();
    int s = base[b], e = base[b + 1];
    for (int i = s + tid; i < e; i += 256) atomicAdd(&h[ecoarse[i] >> 20], 1);
    __syncthreads();
    if (tid == 0) {
        int run = 0;
        for (int i = 0; i < 64; ++i) { off[i] = run; run += h[i]; }
    }
    __syncthreads();
    if (tid < 64) {
        int node = b * 64 + tid;
        if (node < N) {
            rowp[node] = s + off[tid];
            dis[node] = rsqrtf((float)h[tid] + 1.0f);   // in-degree + self-loop
        }
        h[tid] = off[tid];   // reuse as cursors
    }
    if (b == 0 && tid == 0) rowp[N] = E;
    __syncthreads();
    for (int i = s + tid; i < e; i += 256) {
        unsigned v = ecoarse[i];
        int dl = v >> 20;
        int pos = atomicAdd(&h[dl], 1);
        csr[s + pos] = v & 0xFFFFF;
    }
}

// ---------------- weight prep: transpose + convert to bf16 ----------------

__global__ void wprep(const float* __restrict__ W1, const float* __restrict__ convW,
                      const float* __restrict__ W2, unsigned short* __restrict__ W1t,
                      unsigned short* __restrict__ convWt, unsigned short* __restrict__ W2t) {
    int r = blockIdx.x;
    int k = threadIdx.x;
    const float* src;
    unsigned short* dst;
    int ncols, n;
    if (r < 128) { src = W1; dst = W1t; n = r; ncols = 128; }
    else if (r < 640) {
        int l = (r - 128) >> 7; n = (r - 128) & 127;
        src = convW + (size_t)l * 16384; dst = convWt + (size_t)l * 16384; ncols = 128;
    } else { src = W2; dst = W2t; n = r - 640; ncols = 64; }
    dst[(size_t)n * 128 + k] = f2bf(src[(size_t)k * ncols + n]);
}

__global__ void xcast(const float* __restrict__ x, unsigned short* __restrict__ xb, int n8) {
    int i = blockIdx.x * blockDim.x + threadIdx.x;
    if (i >= n8) return;
    float4 v0 = *(const float4*)&x[(size_t)i * 8];
    float4 v1 = *(const float4*)&x[(size_t)i * 8 + 4];
    u16x8 o;
    o[0] = f2bf(v0.x); o[1] = f2bf(v0.y); o[2] = f2bf(v0.z); o[3] = f2bf(v0.w);
    o[4] = f2bf(v1.x); o[5] = f2bf(v1.y); o[6] = f2bf(v1.z); o[7] = f2bf(v1.w);
    *(u16x8*)&xb[(size_t)i * 8] = o;
}

// ---------------- MFMA GEMM: C[n,128] = A[n,128] @ Wt^T (+bias), all bf16 ----------------

template <bool BIAS>
__global__ __launch_bounds__(256, 2) void gemm128_mfma(
    const unsigned short* __restrict__ A, const unsigned short* __restrict__ Bt,
    const float* __restrict__ bias, unsigned short* __restrict__ C, int nrows) {
    int wid = threadIdx.x >> 6, lane = threadIdx.x & 63;
    int l15 = lane & 15, l4 = lane >> 4;

    bf16x8 b[8][4];
#pragma unroll
    for (int nt = 0; nt < 8; ++nt)
#pragma unroll
        for (int ks = 0; ks < 4; ++ks)
            b[nt][ks] = *(const bf16x8*)&Bt[(size_t)(nt * 16 + l15) * 128 + ks * 32 + l4 * 8];
    float bb[8];
    if (BIAS) {
#pragma unroll
        for (int nt = 0; nt < 8; ++nt) bb[nt] = bias[nt * 16 + l15];
    }

    for (int s2 = 0; s2 < 2; ++s2) {
        int row0 = (blockIdx.x * 8 + wid * 2 + s2) * 16;
        if (row0 >= nrows) break;
        int ar = min(row0 + l15, nrows - 1);
        bf16x8 a[4];
#pragma unroll
        for (int ks = 0; ks < 4; ++ks)
            a[ks] = *(const bf16x8*)&A[(size_t)ar * 128 + ks * 32 + l4 * 8];
        f32x4 acc[8] = {};
#pragma unroll
        for (int ks = 0; ks < 4; ++ks)
#pragma unroll
            for (int nt = 0; nt < 8; ++nt)
                acc[nt] = __builtin_amdgcn_mfma_f32_16x16x32_bf16(a[ks], b[nt][ks], acc[nt], 0, 0, 0);
#pragma unroll
        for (int nt = 0; nt < 8; ++nt) {
            int col = nt * 16 + l15;
#pragma unroll
            for (int r = 0; r < 4; ++r) {
                int row = row0 + l4 * 4 + r;
                if (row < nrows) {
                    float v = acc[nt][r];
                    if (BIAS) v += bb[nt];
                    C[(size_t)row * 128 + col] = f2bf(v);
                }
            }
        }
    }
}

// ---------------- final GEMM: out = 0.6*Z1@W2 + 0.1*(Z2+Z3+Z4+Z5)@W2 + b2 ----------------

__global__ __launch_bounds__(256, 2) void gemm_final(
    const unsigned short* __restrict__ z0, const unsigned short* __restrict__ z1,
    const unsigned short* __restrict__ z2, const unsigned short* __restrict__ z3,
    const unsigned short* __restrict__ z4, const unsigned short* __restrict__ Bt,
    const float* __restrict__ bias, float* __restrict__ out, int nrows) {
    int wid = threadIdx.x >> 6, lane = threadIdx.x & 63;
    int l15 = lane & 15, l4 = lane >> 4;

    bf16x8 b[4][4];
#pragma unroll
    for (int nt = 0; nt < 4; ++nt)
#pragma unroll
        for (int ks = 0; ks < 4; ++ks)
            b[nt][ks] = *(const bf16x8*)&Bt[(size_t)(nt * 16 + l15) * 128 + ks * 32 + l4 * 8];
    float bb[4];
#pragma unroll
    for (int nt = 0; nt < 4; ++nt) bb[nt] = bias[nt * 16 + l15];

    const unsigned short* zs[5] = { z0, z1, z2, z3, z4 };

    for (int s2 = 0; s2 < 2; ++s2) {
        int row0 = (blockIdx.x * 8 + wid * 2 + s2) * 16;
        if (row0 >= nrows) break;
        int ar = min(row0 + l15, nrows - 1);
        bf16x8 a[5][4];
#pragma unroll
        for (int st = 0; st < 5; ++st)
#pragma unroll
            for (int ks = 0; ks < 4; ++ks)
                a[st][ks] = *(const bf16x8*)&zs[st][(size_t)ar * 128 + ks * 32 + l4 * 8];
        f32x4 acc0[4] = {};
        f32x4 acc1[4] = {};
#pragma unroll
        for (int st = 0; st < 5; ++st)
#pragma unroll
            for (int ks = 0; ks < 4; ++ks)
#pragma unroll
                for (int nt = 0; nt < 4; ++nt) {
                    if (st == 0)
                        acc0[nt] = __builtin_amdgcn_mfma_f32_16x16x32_bf16(a[0][ks], b[nt][ks], acc0[nt], 0, 0, 0);
                    else
                        acc1[nt] = __builtin_amdgcn_mfma_f32_16x16x32_bf16(a[st][ks], b[nt][ks], acc1[nt], 0, 0, 0);
                }
#pragma unroll
        for (int nt = 0; nt < 4; ++nt) {
            int col = nt * 16 + l15;
#pragma unroll
            for (int r = 0; r < 4; ++r) {
                int row = row0 + l4 * 4 + r;
                if (row < nrows)
                    out[(size_t)row * 64 + col] = 0.6f * acc0[nt][r] + 0.1f * acc1[nt][r] + bb[nt];
            }
        }
    }
}

// ---------------- fused SpMM(bf16 gather) + self-loop + bias + ReLU, bf16 out ----------------
// 16 lanes/node; src-only CSR; w = dis[src], dis[dst] factored out; 8-deep gather pipeline.

__global__ __launch_bounds__(256) void spmm_kernel(
    const unsigned short* __restrict__ xwb, const int* __restrict__ rowp,
    const unsigned* __restrict__ csr, const float* __restrict__ dis,
    const float* __restrict__ bias, unsigned short* __restrict__ Z, int n) {
    int l = threadIdx.x & 15;
    int node = blockIdx.x * 16 + (threadIdx.x >> 4);
    if (node >= n) return;
    const u16x8* xw8 = (const u16x8*)xwb;

    float acc[8] = {};
    int beg = rowp[node], end = rowp[node + 1];
    int e = beg;
    for (; e + 8 <= end; e += 8) {
        unsigned s[8];
        float w[8];
        u16x8 xv[8];
#pragma unroll
        for (int q = 0; q < 8; ++q) s[q] = csr[e + q];
#pragma unroll
        for (int q = 0; q < 8; ++q) w[q] = dis[s[q]];
#pragma unroll
        for (int q = 0; q < 8; ++q) xv[q] = xw8[(size_t)s[q] * 16 + l];
#pragma unroll
        for (int q = 0; q < 8; ++q)
#pragma unroll
            for (int j = 0; j < 8; ++j) acc[j] = fmaf(w[q], bf2f(xv[q][j]), acc[j]);
    }
    for (; e < end; ++e) {
        unsigned s0 = csr[e];
        float w0 = dis[s0];
        u16x8 x0 = xw8[(size_t)s0 * 16 + l];
#pragma unroll
        for (int j = 0; j < 8; ++j) acc[j] = fmaf(w0, bf2f(x0[j]), acc[j]);
    }

    float d = dis[node];
    float d2 = d * d;
    u16x8 xs = xw8[(size_t)node * 16 + l];
    float4 b0 = *(const float4*)&bias[l * 8];
    float4 b1 = *(const float4*)&bias[l * 8 + 4];
    float bbv[8] = { b0.x, b0.y, b0.z, b0.w, b1.x, b1.y, b1.z, b1.w };
    u16x8 ov;
#pragma unroll
    for (int j = 0; j < 8; ++j)
        ov[j] = f2bf(fmaxf(fmaf(d, acc[j], fmaf(d2, bf2f(xs[j]), bbv[j])), 0.f));
    *(u16x8*)&Z[(size_t)node * HID + l * 8] = ov;
}

// ---------------- launcher ----------------

extern "C" void kernel_launch(void* const* d_in, const int* in_sizes, int n_in,
                              void* d_out, int out_size, void* d_ws, size_t ws_size,
                              hipStream_t stream) {
    const float* x     = (const float*)d_in[0];
    const int*   ei    = (const int*)d_in[1];
    const float* W1    = (const float*)d_in[2];
    const float* b1    = (const float*)d_in[3];
    const float* convW = (const float*)d_in[4];
    const float* convB = (const float*)d_in[5];
    const float* W2    = (const float*)d_in[6];
    const float* b2    = (const float*)d_in[7];

    const int N = in_sizes[0] / HID;
    const int E = in_sizes[1] / 2;
    const int* src = ei;
    const int* dst = ei + E;
    const int nbuck = (N + 63) / 64;
    const int nchunks = (E + CHUNK - 1) / CHUNK;

    char* p = (char*)d_ws;
    auto alloc = [&](size_t bytes) {
        void* q = (void*)p;
        p += (bytes + 255) & ~(size_t)255;
        return q;
    };
    float* dis      = (float*)alloc((size_t)N * 4);
    int*   rowp     = (int*)alloc((size_t)(N + 1) * 4);
    int*   base     = (int*)alloc((size_t)(nbuck + 1) * 4);
    int*   colsum   = (int*)alloc((size_t)nbuck * 4);
    int*   cnt2d    = (int*)alloc((size_t)nchunks * nbuck * 4);
    unsigned* ecoarse = (unsigned*)alloc((size_t)E * 4);
    unsigned* csr   = (unsigned*)alloc((size_t)E * 4);
    unsigned short* xb = (unsigned short*)alloc((size_t)N * HID * 2);
    unsigned short* xw = (unsigned short*)alloc((size_t)N * HID * 2);
    unsigned short* Zs[5];
    for (int i = 0; i < 4; ++i) Zs[i] = (unsigned short*)alloc((size_t)N * HID * 2);
    Zs[4] = xb;   // alias: xb dead after gemm1
    unsigned short* W1t    = (unsigned short*)alloc(128 * 128 * 2);
    unsigned short* convWt = (unsigned short*)alloc((size_t)NLAYERS * 128 * 128 * 2);
    unsigned short* W2t    = (unsigned short*)alloc(64 * 128 * 2);

    const int gemmBlocks = (N + 127) / 128;

    // --- weight prep + x cast ---
    wprep<<<704, 128, 0, stream>>>(W1, convW, W2, W1t, convWt, W2t);
    xcast<<<(N * 16 + 255) / 256, 256, 0, stream>>>(x, xb, N * 16);

    // --- graph preprocessing: two-level deterministic counting sort ---
    bin1<<<nchunks, 256, 0, stream>>>(dst, cnt2d, E, nbuck);
    colscan<<<(nbuck + 3) / 4, 256, 0, stream>>>(cnt2d, colsum, nchunks, nbuck);
    basescan<<<1, 256, 0, stream>>>(colsum, base, nbuck);
    bin2<<<nchunks, 256, 0, stream>>>(src, dst, cnt2d, base, ecoarse, E, nbuck);
    finesort<<<nbuck, 256, 0, stream>>>(ecoarse, base, dis, csr, rowp, N, E);

    // --- Z1 = bf16(x @ W1 + b1) ---
    gemm128_mfma<true><<<gemmBlocks, 256, 0, stream>>>(xb, W1t, b1, Zs[0], N);

    // --- 4 GCN layers ---
    for (int l = 0; l < NLAYERS; ++l) {
        gemm128_mfma<false><<<gemmBlocks, 256, 0, stream>>>(
            Zs[l], convWt + (size_t)l * 16384, nullptr, xw, N);
        spmm_kernel<<<(N + 15) / 16, 256, 0, stream>>>(
            xw, rowp, csr, dis, convB + (size_t)l * HID, Zs[l + 1], N);
    }

    // --- out = 0.6*Z1@W2 + 0.1*(Z2+..+Z5)@W2 + b2 ---
    gemm_final<<<gemmBlocks, 256, 0, stream>>>(
        Zs[0], Zs[1], Zs[2], Zs[3], Zs[4], W2t, b2, (float*)d_out, N);
}